// Round 1
// baseline (471.207 us; speedup 1.0000x reference)
//
#include <hip/hip_runtime.h>

#define ROW 120
#define CHUNK 16   // rows per block iteration

// ---------------------------------------------------------------------------
// Kernel 1: per-row norms of the 16 3-vectors and 8 5-vectors, clamped at
// 1e-6, summed over all rows into sums[0..15] (vec) and sums[16..23] (ten).
// ---------------------------------------------------------------------------
__global__ __launch_bounds__(256) void reduce_norms(const float* __restrict__ x,
                                                    float* __restrict__ sums,
                                                    int N) {
    __shared__ float lds[CHUNK * 88];   // cols 32..119 of each staged row
    __shared__ float red[256];
    const int tid = threadIdx.x;

    float accV = 0.f;   // vec channel = tid & 15
    float accT = 0.f;   // ten channel = tid & 7  (tid < 128 only)

    const int nChunks = (N + CHUNK - 1) / CHUNK;
    for (int ch = blockIdx.x; ch < nChunks; ch += gridDim.x) {
        const int row0 = ch * CHUNK;
        // stage cols 32..119 (22 float4 per row)
        for (int i = tid; i < CHUNK * 22; i += 256) {
            const int r = i / 22, q = i - r * 22;
            if (row0 + r < N) {
                const float4 v = *(const float4*)(x + (size_t)(row0 + r) * ROW + 32 + q * 4);
                *(float4*)(lds + r * 88 + q * 4) = v;
            }
        }
        __syncthreads();
        {   // 16 rows x 16 vec channels = 256 threads
            const int r = tid >> 4, v = tid & 15;
            if (row0 + r < N) {
                const float* p = lds + r * 88 + 3 * v;
                const float n = sqrtf(p[0]*p[0] + p[1]*p[1] + p[2]*p[2]);
                accV += fmaxf(n, 1e-6f);
            }
        }
        if (tid < 128) {  // 16 rows x 8 ten channels = 128 threads
            const int r = tid >> 3, c = tid & 7;
            if (row0 + r < N) {
                const float* p = lds + r * 88 + 48 + 5 * c;
                const float n = sqrtf(p[0]*p[0] + p[1]*p[1] + p[2]*p[2]
                                    + p[3]*p[3] + p[4]*p[4]);
                accT += fmaxf(n, 1e-6f);
            }
        }
        __syncthreads();
    }

    // block-level reduction, then one atomicAdd per channel per block
    red[tid] = accV;
    __syncthreads();
    if (tid < 16) {
        float s = 0.f;
        #pragma unroll
        for (int k = 0; k < 16; ++k) s += red[tid + 16 * k];
        atomicAdd(&sums[tid], s);
    }
    __syncthreads();
    red[tid] = (tid < 128) ? accT : 0.f;
    __syncthreads();
    if (tid < 8) {
        float s = 0.f;
        #pragma unroll
        for (int k = 0; k < 16; ++k) s += red[tid + 8 * k];
        atomicAdd(&sums[16 + tid], s);
    }
}

// ---------------------------------------------------------------------------
// Kernel 2: LayerNorm on cols 0..31, rescale vec/ten groups by
// mean_norm[channel] / max(row_norm, 1e-6). Fully LDS-staged, float4 I/O.
// ---------------------------------------------------------------------------
__global__ __launch_bounds__(256) void finalize(const float* __restrict__ x,
                                                const float* __restrict__ w,
                                                const float* __restrict__ b,
                                                const float* __restrict__ sums,
                                                float* __restrict__ out,
                                                int N, float invN) {
    __shared__ float lds[CHUNK * ROW];
    const int tid = threadIdx.x;
    const int l   = tid & 15;

    const float meanV = sums[tid & 15] * invN;          // vec channel mean norm
    const float meanT = sums[16 + (tid & 7)] * invN;    // ten channel mean norm
    const float w0 = w[2 * l], w1 = w[2 * l + 1];
    const float b0 = b[2 * l], b1 = b[2 * l + 1];

    const int nChunks = (N + CHUNK - 1) / CHUNK;
    for (int ch = blockIdx.x; ch < nChunks; ch += gridDim.x) {
        const int row0 = ch * CHUNK;
        // stage 16 full rows (30 float4 each)
        for (int i = tid; i < CHUNK * 30; i += 256) {
            const int r = i / 30, q = i - r * 30;
            if (row0 + r < N)
                *(float4*)(lds + r * ROW + q * 4) =
                    *(const float4*)(x + (size_t)(row0 + r) * ROW + q * 4);
        }
        __syncthreads();

        // --- LayerNorm: 16 lanes per row, 2 scalars per lane ---
        {
            const int r = tid >> 4;
            float* base = lds + r * ROW;
            const float x0 = base[2 * l], x1 = base[2 * l + 1];
            float s  = x0 + x1;
            float sq = x0 * x0 + x1 * x1;
            #pragma unroll
            for (int m = 1; m < 16; m <<= 1) {
                s  += __shfl_xor(s, m);
                sq += __shfl_xor(sq, m);
            }
            const float mu   = s * (1.f / 32.f);
            const float var  = sq * (1.f / 32.f) - mu * mu;
            const float rstd = rsqrtf(var + 1e-5f);
            if (row0 + r < N) {
                base[2 * l]     = (x0 - mu) * rstd * w0 + b0;
                base[2 * l + 1] = (x1 - mu) * rstd * w1 + b1;
            }
        }
        // --- vec rescale: one thread per (row, vec channel) ---
        {
            const int r = tid >> 4, v = tid & 15;
            if (row0 + r < N) {
                float* p = lds + r * ROW + 32 + 3 * v;
                const float n  = sqrtf(p[0]*p[0] + p[1]*p[1] + p[2]*p[2]);
                const float sc = meanV / fmaxf(n, 1e-6f);
                p[0] *= sc; p[1] *= sc; p[2] *= sc;
            }
        }
        // --- ten rescale: one thread per (row, ten channel) ---
        if (tid < 128) {
            const int r = tid >> 3, c = tid & 7;
            if (row0 + r < N) {
                float* p = lds + r * ROW + 80 + 5 * c;
                const float n  = sqrtf(p[0]*p[0] + p[1]*p[1] + p[2]*p[2]
                                     + p[3]*p[3] + p[4]*p[4]);
                const float sc = meanT / fmaxf(n, 1e-6f);
                #pragma unroll
                for (int j = 0; j < 5; ++j) p[j] *= sc;
            }
        }
        __syncthreads();

        // coalesced float4 store
        for (int i = tid; i < CHUNK * 30; i += 256) {
            const int r = i / 30, q = i - r * 30;
            if (row0 + r < N)
                *(float4*)(out + (size_t)(row0 + r) * ROW + q * 4) =
                    *(const float4*)(lds + r * ROW + q * 4);
        }
        __syncthreads();
    }
}

extern "C" void kernel_launch(void* const* d_in, const int* in_sizes, int n_in,
                              void* d_out, int out_size, void* d_ws, size_t ws_size,
                              hipStream_t stream) {
    const float* x = (const float*)d_in[0];
    const float* w = (const float*)d_in[1];
    const float* b = (const float*)d_in[2];
    float* out  = (float*)d_out;
    float* sums = (float*)d_ws;
    const int N = in_sizes[0] / ROW;

    hipMemsetAsync(d_ws, 0, 24 * sizeof(float), stream);  // ws is re-poisoned each call
    reduce_norms<<<2048, 256, 0, stream>>>(x, sums, N);
    finalize<<<4096, 256, 0, stream>>>(x, w, b, sums, out, N, 1.0f / (float)N);
}